// Round 8
// baseline (53.268 us; speedup 1.0000x reference)
//
#include <hip/hip_runtime.h>
#include <math.h>

// Problem constants: N=2048, L=8, D=64, M=N=2048.
#define N_B 2048
#define L_L 8
#define D_D 64

typedef short bf16x8 __attribute__((ext_vector_type(8)));
typedef float f32x4 __attribute__((ext_vector_type(4)));
typedef unsigned short ushort8v __attribute__((ext_vector_type(8)));

#if __has_builtin(__builtin_amdgcn_exp2f)
#define EXP2(x) __builtin_amdgcn_exp2f(x)
#else
#define EXP2(x) exp2f(x)
#endif

// Split fp32 x into bf16 hi + bf16 lo (RTNE each), x ≈ hi+lo to ~2^-17 rel.
// Returns hi in high 16 bits, lo in low 16 bits.
__device__ __forceinline__ unsigned split_bf16_pack(float x) {
  unsigned u = __float_as_uint(x);
  unsigned rb = u + 0x7FFFu + ((u >> 16) & 1u);
  unsigned hbits = rb & 0xFFFF0000u;
  float res = x - __uint_as_float(hbits);
  unsigned u2 = __float_as_uint(res);
  unsigned rb2 = u2 + 0x7FFFu + ((u2 >> 16) & 1u);
  return hbits | (rb2 >> 16);
}

// Split 8 contiguous floats (optionally scaled) into hi/lo ushort8 vectors.
__device__ __forceinline__ void split8(const float* __restrict__ src,
                                       float scale, ushort8v& H, ushort8v& L,
                                       float* ssq) {
  float4 v0 = *(const float4*)(src);
  float4 v1 = *(const float4*)(src + 4);
  float vv[8] = {v0.x, v0.y, v0.z, v0.w, v1.x, v1.y, v1.z, v1.w};
  #pragma unroll
  for (int t = 0; t < 8; ++t) {
    if (ssq) *ssq += vv[t] * vv[t];
    unsigned p = split_bf16_pack(scale * vv[t]);
    H[t] = (unsigned short)(p >> 16);
    L[t] = (unsigned short)(p & 0xFFFF);
  }
}

// ---------------------------------------------------------------------------
// prep: one-time bf16 hi/lo split of all MFMA operands.
//  blocks [0,512):   e  (16384x64, scaled by se) -> esh/esl, en2 (raw ssq)
//  blocks [512,576): z  (2048x64)                -> zsh/zsl
//  blocks [576,592): encW (512x64)               -> ewh/ewl
//  blocks [592,608): decW (64x512)               -> dwh/dwl
// ---------------------------------------------------------------------------
__global__ __launch_bounds__(256) void prep_kernel(
    const float* __restrict__ z, const float* __restrict__ encW,
    const float* __restrict__ e, const float* __restrict__ decW,
    const float* __restrict__ log_sigma,
    unsigned short* __restrict__ zsh, unsigned short* __restrict__ zsl,
    unsigned short* __restrict__ ewh, unsigned short* __restrict__ ewl,
    unsigned short* __restrict__ esh, unsigned short* __restrict__ esl,
    float* __restrict__ en2G,
    unsigned short* __restrict__ dwh, unsigned short* __restrict__ dwl) {
  const int b = blockIdx.x;
  ushort8v H, L;
  if (b < 512) {
    const float ls = log_sigma[0];
    const float sig = __expf(ls);
    const float ap = (-1.0f / (2.0f * sig * sig)) * 1.4426950408889634f;
    const float se = -2.0f * ap;
    int t = b * 256 + threadIdx.x;          // 8 threads per e-row
    size_t off = (size_t)t * 8;
    float ssq = 0.f;
    split8(e + off, se, H, L, &ssq);
    *(ushort8v*)(esh + off) = H;
    *(ushort8v*)(esl + off) = L;
    ssq += __shfl_xor(ssq, 1);
    ssq += __shfl_xor(ssq, 2);
    ssq += __shfl_xor(ssq, 4);
    if ((t & 7) == 0) en2G[t >> 3] = ssq;
  } else if (b < 576) {
    int t = (b - 512) * 256 + threadIdx.x;
    size_t off = (size_t)t * 8;
    split8(z + off, 1.0f, H, L, nullptr);
    *(ushort8v*)(zsh + off) = H;
    *(ushort8v*)(zsl + off) = L;
  } else if (b < 592) {
    int t = (b - 576) * 256 + threadIdx.x;
    size_t off = (size_t)t * 8;
    split8(encW + off, 1.0f, H, L, nullptr);
    *(ushort8v*)(ewh + off) = H;
    *(ushort8v*)(ewl + off) = L;
  } else {
    int t = (b - 592) * 256 + threadIdx.x;
    size_t off = (size_t)t * 8;
    split8(decW + off, 1.0f, H, L, nullptr);
    *(ushort8v*)(dwh + off) = H;
    *(ushort8v*)(dwl + off) = L;
  }
}

// ---------------------------------------------------------------------------
// encode: h = z @ encW^T + encb as z_multi[l][n][d], all operands pre-split.
// grid 256 = nt(32) x l(8). Emits zm (fp32 output), zh/zl (split of h),
// ez (= exp2(ap*||h_row||^2)).
// ---------------------------------------------------------------------------
__global__ __launch_bounds__(256) void encode_kernel(
    const unsigned short* __restrict__ zsh, const unsigned short* __restrict__ zsl,
    const unsigned short* __restrict__ ewh, const unsigned short* __restrict__ ewl,
    const float* __restrict__ encb, const float* __restrict__ log_sigma,
    float* __restrict__ zm,
    unsigned short* __restrict__ zhG, unsigned short* __restrict__ zlG,
    float* __restrict__ ezG) {
  const int l = blockIdx.x & 7;
  const int nt = blockIdx.x >> 3;
  const int n0 = nt << 6;
  const int tid = threadIdx.x;
  const int lane = tid & 63;
  const int wave = tid >> 6;
  const int bm = lane & 15;
  const int kg = lane >> 4;
  const int k0 = kg << 3;

  const float ls = log_sigma[0];
  const float sig = __expf(ls);
  const float ap = (-1.0f / (2.0f * sig * sig)) * 1.4426950408889634f;

  bf16x8 Bh0[4], Bh1[4], Bl0[4], Bl1[4];
  #pragma unroll
  for (int ms = 0; ms < 4; ++ms) {
    size_t base = ((size_t)(l * 64 + ms * 16 + bm)) * 64 + k0;
    Bh0[ms] = *(const bf16x8*)(ewh + base);
    Bh1[ms] = *(const bf16x8*)(ewh + base + 32);
    Bl0[ms] = *(const bf16x8*)(ewl + base);
    Bl1[ms] = *(const bf16x8*)(ewl + base + 32);
  }
  bf16x8 ah0, ah1, al0, al1;
  {
    size_t base = ((size_t)(n0 + (wave << 4) + bm)) * 64 + k0;
    ah0 = *(const bf16x8*)(zsh + base);
    ah1 = *(const bf16x8*)(zsh + base + 32);
    al0 = *(const bf16x8*)(zsl + base);
    al1 = *(const bf16x8*)(zsl + base + 32);
  }

  float sq[4] = {0.f, 0.f, 0.f, 0.f};
  #pragma unroll
  for (int ms = 0; ms < 4; ++ms) {
    float bi = encb[l * 64 + ms * 16 + bm];
    f32x4 acc = {bi, bi, bi, bi};
    acc = __builtin_amdgcn_mfma_f32_16x16x32_bf16(ah0, Bh0[ms], acc, 0, 0, 0);
    acc = __builtin_amdgcn_mfma_f32_16x16x32_bf16(ah1, Bh1[ms], acc, 0, 0, 0);
    acc = __builtin_amdgcn_mfma_f32_16x16x32_bf16(al0, Bh0[ms], acc, 0, 0, 0);
    acc = __builtin_amdgcn_mfma_f32_16x16x32_bf16(al1, Bh1[ms], acc, 0, 0, 0);
    acc = __builtin_amdgcn_mfma_f32_16x16x32_bf16(ah0, Bl0[ms], acc, 0, 0, 0);
    acc = __builtin_amdgcn_mfma_f32_16x16x32_bf16(ah1, Bl1[ms], acc, 0, 0, 0);
    #pragma unroll
    for (int r = 0; r < 4; ++r) {
      float v = acc[r];
      int nr = n0 + (wave << 4) + (kg << 2) + r;
      size_t idx = ((size_t)(l * N_B + nr)) * 64 + (ms << 4) + bm;
      zm[idx] = v;
      unsigned p = split_bf16_pack(v);
      zhG[idx] = (unsigned short)(p >> 16);
      zlG[idx] = (unsigned short)(p & 0xFFFF);
      sq[r] += v * v;
    }
  }
  #pragma unroll
  for (int r = 0; r < 4; ++r) {
    float s = sq[r];
    s += __shfl_xor(s, 1);
    s += __shfl_xor(s, 2);
    s += __shfl_xor(s, 4);
    s += __shfl_xor(s, 8);
    if (bm == 0)
      ezG[l * N_B + n0 + (wave << 4) + (kg << 2) + r] = EXP2(ap * s);
  }
}

// ---------------------------------------------------------------------------
// lse: grid 1024 = l(8) x mt(32) x nb(4), XCD-swizzled (one l per XCD).
// partial[l][m][nb] = sum_n ez_n * exp2( (-2ap) z_n.e_m ),
// ez_n = exp2(ap*||z_n||^2) precomputed.  unroll 1 + pointer bumps keep
// VGPR < 128 for 4 blocks/CU.
// ---------------------------------------------------------------------------
__global__ __launch_bounds__(256, 4) void lse_kernel(
    const unsigned short* __restrict__ zhG, const unsigned short* __restrict__ zlG,
    const unsigned short* __restrict__ esh, const unsigned short* __restrict__ esl,
    const float* __restrict__ ezG, float* __restrict__ partials) {
  __shared__ float red[4][64];
  const int wgid = (blockIdx.x & 7) * 128 + (blockIdx.x >> 3);
  const int l = wgid >> 7;
  const int mt = (wgid >> 2) & 31;
  const int nb = wgid & 3;
  const int m0 = mt << 6;
  const int tid = threadIdx.x;
  const int lane = tid & 63;
  const int wave = tid >> 6;
  const int bm = lane & 15;
  const int kg = lane >> 4;
  const int k0 = kg << 3;

  bf16x8 Bh0[4], Bh1[4], Bl0[4], Bl1[4];
  #pragma unroll
  for (int ms = 0; ms < 4; ++ms) {
    size_t base = ((size_t)(l * N_B) + m0 + ms * 16 + bm) * 64 + k0;
    Bh0[ms] = *(const bf16x8*)(esh + base);
    Bh1[ms] = *(const bf16x8*)(esh + base + 32);
    Bl0[ms] = *(const bf16x8*)(esl + base);
    Bl1[ms] = *(const bf16x8*)(esl + base + 32);
  }

  float sums[4] = {0.f, 0.f, 0.f, 0.f};
  // start row for this wave: nb*512 + wave*16; step 64 rows per c-iter
  const int nstart = (nb << 9) + (wave << 4);
  const unsigned short* zhP = zhG + ((size_t)(l * N_B) + nstart + bm) * 64 + k0;
  const unsigned short* zlP = zlG + ((size_t)(l * N_B) + nstart + bm) * 64 + k0;
  const float* ezP = ezG + l * N_B + nstart + (kg << 2);

  #pragma unroll 1
  for (int c = 0; c < 8; ++c) {
    bf16x8 ah0 = *(const bf16x8*)(zhP);
    bf16x8 ah1 = *(const bf16x8*)(zhP + 32);
    bf16x8 al0 = *(const bf16x8*)(zlP);
    bf16x8 al1 = *(const bf16x8*)(zlP + 32);
    f32x4 ezv = *(const f32x4*)(ezP);
    zhP += 64 * 64;  zlP += 64 * 64;  ezP += 64;
    #pragma unroll
    for (int ms = 0; ms < 4; ++ms) {
      f32x4 acc = {0.f, 0.f, 0.f, 0.f};
      acc = __builtin_amdgcn_mfma_f32_16x16x32_bf16(ah0, Bh0[ms], acc, 0, 0, 0);
      acc = __builtin_amdgcn_mfma_f32_16x16x32_bf16(ah1, Bh1[ms], acc, 0, 0, 0);
      acc = __builtin_amdgcn_mfma_f32_16x16x32_bf16(al0, Bh0[ms], acc, 0, 0, 0);
      acc = __builtin_amdgcn_mfma_f32_16x16x32_bf16(al1, Bh1[ms], acc, 0, 0, 0);
      acc = __builtin_amdgcn_mfma_f32_16x16x32_bf16(ah0, Bl0[ms], acc, 0, 0, 0);
      acc = __builtin_amdgcn_mfma_f32_16x16x32_bf16(ah1, Bl1[ms], acc, 0, 0, 0);
      sums[ms] = fmaf(ezv[0], EXP2(acc[0]), sums[ms]);
      sums[ms] = fmaf(ezv[1], EXP2(acc[1]), sums[ms]);
      sums[ms] = fmaf(ezv[2], EXP2(acc[2]), sums[ms]);
      sums[ms] = fmaf(ezv[3], EXP2(acc[3]), sums[ms]);
    }
  }

  #pragma unroll
  for (int ms = 0; ms < 4; ++ms) {
    float s = sums[ms];
    s += __shfl_xor(s, 16);
    s += __shfl_xor(s, 32);
    if (lane < 16) red[wave][ms * 16 + lane] = s;
  }
  __syncthreads();
  if (tid < 64) {
    float S = red[0][tid] + red[1][tid] + red[2][tid] + red[3][tid];
    partials[(((size_t)(l * N_B)) + m0 + tid) * 4 + nb] = S;
  }
}

// ---------------------------------------------------------------------------
// zdec: z_dec = h @ decW^T + decb via split-bf16 MFMA over K=512.
// 128 blocks x 4 waves; each wave 4 of 16 K-groups; LDS cross-wave reduce.
// ---------------------------------------------------------------------------
__global__ __launch_bounds__(256) void zdec_kernel(
    const unsigned short* __restrict__ zhG, const unsigned short* __restrict__ zlG,
    const unsigned short* __restrict__ dwh, const unsigned short* __restrict__ dwl,
    const float* __restrict__ decb, float* __restrict__ zdec) {
  __shared__ f32x4 red[4][4][64];
  const int n0 = blockIdx.x << 4;
  const int tid = threadIdx.x;
  const int lane = tid & 63;
  const int wave = tid >> 6;
  const int bm = lane & 15;
  const int kg = lane >> 4;
  const int k0 = kg << 3;

  f32x4 acc[4] = {{0.f, 0.f, 0.f, 0.f}, {0.f, 0.f, 0.f, 0.f},
                  {0.f, 0.f, 0.f, 0.f}, {0.f, 0.f, 0.f, 0.f}};

  #pragma unroll
  for (int jj = 0; jj < 4; ++jj) {
    int j = (wave << 2) + jj;
    int l = j >> 1;
    int off = ((j & 1) << 5) + k0;
    size_t ab = ((size_t)(l * N_B + n0 + bm)) * 64 + off;
    bf16x8 ah = *(const bf16x8*)(zhG + ab);
    bf16x8 al = *(const bf16x8*)(zlG + ab);
    #pragma unroll
    for (int ms = 0; ms < 4; ++ms) {
      int d = (ms << 4) + bm;
      size_t bb = (size_t)d * 512 + (j << 5) + k0;
      bf16x8 bh = *(const bf16x8*)(dwh + bb);
      bf16x8 bl = *(const bf16x8*)(dwl + bb);
      acc[ms] = __builtin_amdgcn_mfma_f32_16x16x32_bf16(ah, bh, acc[ms], 0, 0, 0);
      acc[ms] = __builtin_amdgcn_mfma_f32_16x16x32_bf16(al, bh, acc[ms], 0, 0, 0);
      acc[ms] = __builtin_amdgcn_mfma_f32_16x16x32_bf16(ah, bl, acc[ms], 0, 0, 0);
    }
  }

  #pragma unroll
  for (int ms = 0; ms < 4; ++ms) red[wave][ms][lane] = acc[ms];
  __syncthreads();
  if (wave == 0) {
    #pragma unroll
    for (int ms = 0; ms < 4; ++ms) {
      f32x4 s = red[0][ms][lane];
      #pragma unroll
      for (int w = 1; w < 4; ++w) {
        f32x4 t = red[w][ms][lane];
        s[0] += t[0]; s[1] += t[1]; s[2] += t[2]; s[3] += t[3];
      }
      float bd = decb[(ms << 4) + bm];
      #pragma unroll
      for (int r = 0; r < 4; ++r)
        zdec[(size_t)(n0 + (kg << 2) + r) * 64 + (ms << 4) + bm] = s[r] + bd;
    }
  }
}

// ---------------------------------------------------------------------------
// finalize: single block, 1024 threads. Per (l,m): S = sum of 4 nb-partials,
// val = ln2*(ap*en2 + log2 S); reduce 16384 vals -> scalar.
// ---------------------------------------------------------------------------
__global__ __launch_bounds__(1024) void finalize_kernel(
    const float* __restrict__ partials, const float* __restrict__ en2G,
    const float* __restrict__ log_sigma, float* __restrict__ out_scalar) {
  __shared__ float buf[16];
  const int tid = threadIdx.x;
  const float ls = log_sigma[0];
  const float sig = __expf(ls);
  const float ap = (-1.0f / (2.0f * sig * sig)) * 1.4426950408889634f;

  float local = 0.f;
  #pragma unroll 4
  for (int i = 0; i < 16; ++i) {
    int idx = tid + (i << 10);
    f32x4 p = *(const f32x4*)(partials + (size_t)idx * 4);
    float S = p[0] + p[1] + p[2] + p[3];
    local += ap * en2G[idx] + __log2f(S);
  }
  #pragma unroll
  for (int off = 32; off; off >>= 1) local += __shfl_down(local, off);
  if ((tid & 63) == 0) buf[tid >> 6] = local;
  __syncthreads();
  if (tid == 0) {
    float t = 0.f;
    #pragma unroll
    for (int w = 0; w < 16; ++w) t += buf[w];
    float total = 0.69314718055994531f * t;
    float val = -total / (float)(L_L * N_B)
              + 0.5f * (float)D_D * (2.0f * ls - 1.0f)
              + logf((float)N_B);
    *out_scalar = val;
  }
}

extern "C" void kernel_launch(void* const* d_in, const int* in_sizes, int n_in,
                              void* d_out, int out_size, void* d_ws, size_t ws_size,
                              hipStream_t stream) {
  const float* z    = (const float*)d_in[0];
  const float* e    = (const float*)d_in[1];
  const float* encW = (const float*)d_in[2];
  const float* encb = (const float*)d_in[3];
  const float* decW = (const float*)d_in[4];
  const float* decb = (const float*)d_in[5];
  const float* lsg  = (const float*)d_in[6];

  float* out    = (float*)d_out;
  float* zdec   = out;                                // [2048*64]
  float* zmulti = out + N_B * D_D;                    // [8*2048*64]
  float* lse    = out + N_B * D_D + L_L * N_B * D_D;  // [1]

  float* partials = (float*)d_ws;                     // [65536]
  float* ez       = partials + 65536;                 // [16384]
  float* en2      = ez + 16384;                       // [16384]
  unsigned short* us = (unsigned short*)(en2 + 16384);
  unsigned short* zsh = us;                 // [131072]
  unsigned short* zsl = zsh + 131072;
  unsigned short* ewh = zsl + 131072;       // [32768]
  unsigned short* ewl = ewh + 32768;
  unsigned short* esh = ewl + 32768;        // [1048576]
  unsigned short* esl = esh + 1048576;
  unsigned short* dwh = esl + 1048576;      // [32768]
  unsigned short* dwl = dwh + 32768;
  unsigned short* zh  = dwl + 32768;        // [1048576]
  unsigned short* zl  = zh + 1048576;

  prep_kernel<<<608, 256, 0, stream>>>(z, encW, e, decW, lsg,
                                       zsh, zsl, ewh, ewl, esh, esl, en2,
                                       dwh, dwl);
  encode_kernel<<<256, 256, 0, stream>>>(zsh, zsl, ewh, ewl, encb, lsg,
                                         zmulti, zh, zl, ez);
  lse_kernel<<<1024, 256, 0, stream>>>(zh, zl, esh, esl, ez, partials);
  zdec_kernel<<<128, 256, 0, stream>>>(zh, zl, dwh, dwl, decb, zdec);
  finalize_kernel<<<1, 1024, 0, stream>>>(partials, en2, lsg, lse);
}